// Round 10
// baseline (299.035 us; speedup 1.0000x reference)
//
#include <hip/hip_runtime.h>
#include <hip/hip_bf16.h>

#define DIM 64
#define CBN 512              // nodes per coarse bucket
#define CBSH 9               // log2(CBN)
#define NCB 256              // max coarse buckets (N <= 131072)
#define BKN 32               // nodes per fine slice (gather)
#define BKSH 5               // log2(BKN)
#define FPC 16               // fine slices per coarse bucket (CBN/BKN)
#define SORTB 512            // blocks for hist/place
#define SORTT 512            // threads per hist/place block
#define CAP 2048             // per-fine-slice LDS record capacity; mean ~1024

__device__ inline float fast_tanh(float x) {
    float e = __expf(2.0f * x);
    return 1.0f - 2.0f / (e + 1.0f);
}

// ---------- gates: per-node dots; pack {gate_dot, d} float2; bf16 copy of h ----------
__global__ void fa_node_gates(const float* __restrict__ h,
                              const float* __restrict__ gate_W,
                              const float* __restrict__ dn,
                              float2* __restrict__ gdd,
                              float2* __restrict__ gss,
                              __hip_bfloat16* __restrict__ hb,   // may be null
                              int N) {
    int gid  = blockIdx.x * blockDim.x + threadIdx.x;
    int node = gid >> 6;
    int lane = threadIdx.x & 63;
    if (node >= N) return;
    float x = h[(size_t)node * DIM + lane];
    if (hb) hb[(size_t)node * DIM + lane] = __float2bfloat16(x);
    float a = x * gate_W[lane];
    float b = x * gate_W[DIM + lane];
    #pragma unroll
    for (int off = 32; off >= 1; off >>= 1) {
        a += __shfl_xor(a, off, 64);
        b += __shfl_xor(b, off, 64);
    }
    if (lane == 0) {
        float dv = dn[node];
        gdd[node] = make_float2(a, dv);
        gss[node] = make_float2(b, dv);
    }
}

// ---------- pass 1: per-block coarse histogram (cnt[blk*NCB + cb]) ----------
__global__ void fa_hist1(const int* __restrict__ edst, int* __restrict__ cnt, int E) {
    __shared__ int lh[NCB];
    int tid = threadIdx.x;
    for (int i = tid; i < NCB; i += blockDim.x) lh[i] = 0;
    __syncthreads();
    int chunk = (E + gridDim.x - 1) / gridDim.x;
    int c0 = blockIdx.x * chunk;
    int c1 = min(E, c0 + chunk);
    for (int i = c0 + tid; i < c1; i += blockDim.x)
        atomicAdd(&lh[edst[i] >> CBSH], 1);
    __syncthreads();
    for (int i = tid; i < NCB; i += blockDim.x)
        cnt[blockIdx.x * NCB + i] = lh[i];
}

// ---------- scan A: per-coarse-bucket exclusive prefix over blocks ----------
__global__ void fa_scanA1(int* __restrict__ cnt, int* __restrict__ cbtot) {
    __shared__ int sc[SORTB];
    int cb  = blockIdx.x;
    int tid = threadIdx.x;
    int v = cnt[tid * NCB + cb];
    sc[tid] = v;
    __syncthreads();
    for (int dd = 1; dd < SORTB; dd <<= 1) {
        int t = (tid >= dd) ? sc[tid - dd] : 0;
        __syncthreads();
        sc[tid] += t;
        __syncthreads();
    }
    cnt[tid * NCB + cb] = sc[tid] - v;
    if (tid == SORTB - 1) cbtot[cb] = sc[tid];
}

// ---------- scan B: exclusive scan of coarse totals (all NCB entries defined) ----------
__global__ void fa_scanB1(const int* __restrict__ cbtot, int* __restrict__ cboff, int nbkc) {
    __shared__ int sc[NCB];
    int tid = threadIdx.x;
    int v = (tid < nbkc) ? cbtot[tid] : 0;
    sc[tid] = v;
    __syncthreads();
    for (int dd = 1; dd < NCB; dd <<= 1) {
        int t = (tid >= dd) ? sc[tid - dd] : 0;
        __syncthreads();
        sc[tid] += t;
        __syncthreads();
    }
    cboff[tid] = sc[tid] - v;
}

// ---------- pass 2: gate compute + place record in coarse bucket region ----------
__global__ void fa_place1(const float2* __restrict__ gdd, const float2* __restrict__ gss,
                          const int* __restrict__ esrc, const int* __restrict__ edst,
                          const float* __restrict__ gate_b,
                          const int* __restrict__ cnt, const int* __restrict__ cboff,
                          int2* __restrict__ pairs, int E) {
    __shared__ int lcur[NCB];
    int tid = threadIdx.x;
    for (int i = tid; i < NCB; i += blockDim.x)
        lcur[i] = cboff[i] + cnt[blockIdx.x * NCB + i];
    __syncthreads();
    int chunk = (E + gridDim.x - 1) / gridDim.x;
    int c0 = blockIdx.x * chunk;
    int c1 = min(E, c0 + chunk);
    float gb = gate_b[0];
    for (int i = c0 + tid; i < c1; i += blockDim.x) {
        int t = edst[i];
        int s = esrc[i];
        float2 ad = gdd[t];
        float2 bs = gss[s];
        float g  = fast_tanh(ad.x + bs.x + gb);
        float ev = g * ad.y * bs.y;
        int pos = atomicAdd(&lcur[t >> CBSH], 1);       // LDS atomic
        pairs[pos] = make_int2((s << CBSH) | (t & (CBN - 1)), __float_as_int(ev));
    }
}

// ---------- gather: block per (coarse, fine-slice); filter->LDS sort->reg gather ----------
__global__ __launch_bounds__(256, 4)
void fa_gather5(const __hip_bfloat16* __restrict__ hb,
                const int* __restrict__ cboff, const int* __restrict__ cbtot,
                const int2* __restrict__ pairs,
                float* __restrict__ z, int N, int nbkc) {
    __shared__ int2 buf1[CAP];                   // 16 KB (filtered, unsorted)
    __shared__ int2 buf2[CAP];                   // 16 KB (sorted by node, decoded)
    __shared__ int hist[BKN];
    __shared__ int cur[BKN];
    __shared__ int offl[BKN + 1];
    __shared__ int fill;
    int b   = blockIdx.x;
    int cb  = (b & 7) | ((b >> 7) << 3);         // co-locate 16 siblings per XCD
    int f   = (b >> 3) & 15;
    if (cb >= nbkc) return;
    int tid = threadIdx.x;                       // 256 threads = 4 waves
    int c0 = cboff[cb];
    int c  = cbtot[cb];
    int base_node = (cb << CBSH) + (f << BKSH);
    if (tid < BKN) hist[tid] = 0;
    if (tid == 0) fill = 0;
    __syncthreads();
    // single pass over the coarse region: filter this fine slice into buf1 + hist
    for (int i = tid; i < c; i += 256) {
        int2 r = pairs[c0 + i];
        if (((r.x >> BKSH) & (FPC - 1)) == f) {
            int p = atomicAdd(&fill, 1);
            if (p < CAP) {
                buf1[p] = r;
                atomicAdd(&hist[r.x & (BKN - 1)], 1);
            }
        }
    }
    __syncthreads();
    int kept = fill;
    int wid  = tid >> 6;
    int lane = tid & 63;
    if (kept <= CAP) {
        // 32-wide exclusive scan
        if (tid < BKN) cur[tid] = hist[tid];
        __syncthreads();
        #pragma unroll
        for (int dd = 1; dd < BKN; dd <<= 1) {
            int t = (tid < BKN && tid >= dd) ? cur[tid - dd] : 0;
            __syncthreads();
            if (tid < BKN) cur[tid] += t;
            __syncthreads();
        }
        if (tid < BKN) {
            offl[tid + 1] = cur[tid];
            cur[tid] -= hist[tid];
            if (tid == 0) offl[0] = 0;
        }
        __syncthreads();
        // LDS permute into node-sorted buf2, decoding src
        for (int i = tid; i < kept; i += 256) {
            int2 r = buf1[i];
            int p = atomicAdd(&cur[r.x & (BKN - 1)], 1);
            buf2[p] = make_int2(r.x >> CBSH, r.y);
        }
        __syncthreads();
        // wave-per-node register gather (proven structure)
        for (int ln = wid; ln < BKN; ln += 4) {
            int node = base_node + ln;
            if (node >= N) break;
            int j   = offl[ln];
            int end = offl[ln + 1];
            float a0 = 0.f, a1 = 0.f, a2 = 0.f, a3 = 0.f;
            for (; j + 4 <= end; j += 4) {
                int2 p0 = buf2[j];
                int2 p1 = buf2[j + 1];
                int2 p2 = buf2[j + 2];
                int2 p3 = buf2[j + 3];
                a0 += __bfloat162float(hb[(size_t)p0.x * DIM + lane]) * __int_as_float(p0.y);
                a1 += __bfloat162float(hb[(size_t)p1.x * DIM + lane]) * __int_as_float(p1.y);
                a2 += __bfloat162float(hb[(size_t)p2.x * DIM + lane]) * __int_as_float(p2.y);
                a3 += __bfloat162float(hb[(size_t)p3.x * DIM + lane]) * __int_as_float(p3.y);
            }
            for (; j < end; ++j) {
                int2 p = buf2[j];
                a0 += __bfloat162float(hb[(size_t)p.x * DIM + lane]) * __int_as_float(p.y);
            }
            z[(size_t)node * DIM + lane] = a0 + a1 + a2 + a3;
        }
    } else {
        // adversarial-skew slow path: direct filtered accumulate from global
        for (int ln = wid; ln < BKN; ln += 4) {
            int node = base_node + ln;
            if (node >= N) break;
            int want = (f << BKSH) | ln;
            float acc = 0.f;
            for (int j = c0; j < c0 + c; ++j) {
                int2 p = pairs[j];
                if ((p.x & (CBN - 1)) == want)
                    acc += __bfloat162float(hb[(size_t)(p.x >> CBSH) * DIM + lane])
                           * __int_as_float(p.y);
            }
            z[(size_t)node * DIM + lane] = acc;
        }
    }
}

// ---------- fallback: atomic scatter ----------
__global__ void fa_edge_scatter_atomic(const float* __restrict__ h,
                                       const float2* __restrict__ gdd,
                                       const float2* __restrict__ gss,
                                       const int* __restrict__ esrc,
                                       const int* __restrict__ edst,
                                       const float* __restrict__ gate_b,
                                       float* __restrict__ z, int E) {
    int gid  = blockIdx.x * blockDim.x + threadIdx.x;
    int edge = gid >> 6;
    int lane = threadIdx.x & 63;
    if (edge >= E) return;
    int s = esrc[edge];
    int t = edst[edge];
    float2 ad = gdd[t];
    float2 bs = gss[s];
    float g  = fast_tanh(ad.x + bs.x + gate_b[0]);
    float ev = g * ad.y * bs.y;
    atomicAdd(&z[(size_t)t * DIM + lane], h[(size_t)s * DIM + lane] * ev);
}

extern "C" void kernel_launch(void* const* d_in, const int* in_sizes, int n_in,
                              void* d_out, int out_size, void* d_ws, size_t ws_size,
                              hipStream_t stream) {
    const float* h      = (const float*)d_in[0];
    const float* dn     = (const float*)d_in[1];
    const float* gate_W = (const float*)d_in[2];
    const float* gate_b = (const float*)d_in[3];
    const int*   esrc   = (const int*)d_in[4];
    const int*   edst   = (const int*)d_in[5];
    float*       z      = (float*)d_out;

    int N = in_sizes[1];
    int E = in_sizes[4];
    int nbkc = (N + CBN - 1) >> CBSH;

    // workspace layout
    char* w = (char*)d_ws;
    float2* gdd  = (float2*)w;         w += (size_t)N * 8;
    float2* gss  = (float2*)w;         w += (size_t)N * 8;
    int*   cbtot = (int*)w;            w += (size_t)NCB * 4;
    int*   cboff = (int*)w;            w += (size_t)NCB * 4;
    int*   cnt   = (int*)w;            w += (size_t)SORTB * NCB * 4;    // 512 KB
    w = (char*)(((uintptr_t)w + 63) & ~(uintptr_t)63);
    int2* pairs  = (int2*)w;           w += ((size_t)E + 64) * 8;
    __hip_bfloat16* hb = (__hip_bfloat16*)w;
    w += (size_t)N * DIM * 2;
    size_t required = (size_t)(w - (char*)d_ws);
    size_t atomic_required = (size_t)N * 16;

    bool use_sort = (ws_size >= required) && (nbkc <= NCB);

    fa_node_gates<<<(N + 3) / 4, 256, 0, stream>>>(h, gate_W, dn, gdd, gss,
                                                   use_sort ? hb : (__hip_bfloat16*)nullptr, N);

    if (use_sort) {
        fa_hist1<<<SORTB, SORTT, 0, stream>>>(edst, cnt, E);
        fa_scanA1<<<nbkc, SORTB, 0, stream>>>(cnt, cbtot);
        fa_scanB1<<<1, NCB, 0, stream>>>(cbtot, cboff, nbkc);
        fa_place1<<<SORTB, SORTT, 0, stream>>>(gdd, gss, esrc, edst, gate_b,
                                               cnt, cboff, pairs, E);
        int groups = (nbkc + 7) / 8;
        fa_gather5<<<groups * 128, 256, 0, stream>>>(hb, cboff, cbtot, pairs, z, N, nbkc);
    } else if (ws_size >= atomic_required) {
        hipMemsetAsync(z, 0, (size_t)out_size * sizeof(float), stream);
        fa_edge_scatter_atomic<<<(E + 3) / 4, 256, 0, stream>>>(h, gdd, gss, esrc,
                                                                edst, gate_b, z, E);
    }
}

// Round 11
// 179.728 us; speedup vs baseline: 1.6638x; 1.6638x over previous
//
#include <hip/hip_runtime.h>
#include <hip/hip_bf16.h>

#define DIM 64
#define BKN 64               // nodes per bucket
#define BKSH 6               // log2(BKN)
#define MAXBK 1600           // supports N <= 102400
#define SORTB 512            // blocks for hist/place
#define SORTT 512            // threads per hist/place block
#define CAP 3072             // fused-gather LDS record capacity; mean ~2048

__device__ inline float fast_tanh(float x) {
    float e = __expf(2.0f * x);
    return 1.0f - 2.0f / (e + 1.0f);
}

// ---------- gates: per-node dots; pack {gate_dot, d} float2; bf16 copy of h ----------
__global__ void fa_node_gates(const float* __restrict__ h,
                              const float* __restrict__ gate_W,
                              const float* __restrict__ dn,
                              float2* __restrict__ gdd,
                              float2* __restrict__ gss,
                              __hip_bfloat16* __restrict__ hb,   // may be null
                              int N) {
    int gid  = blockIdx.x * blockDim.x + threadIdx.x;
    int node = gid >> 6;
    int lane = threadIdx.x & 63;
    if (node >= N) return;
    float x = h[(size_t)node * DIM + lane];
    if (hb) hb[(size_t)node * DIM + lane] = __float2bfloat16(x);
    float a = x * gate_W[lane];
    float b = x * gate_W[DIM + lane];
    #pragma unroll
    for (int off = 32; off >= 1; off >>= 1) {
        a += __shfl_xor(a, off, 64);
        b += __shfl_xor(b, off, 64);
    }
    if (lane == 0) {
        float dv = dn[node];
        gdd[node] = make_float2(a, dv);
        gss[node] = make_float2(b, dv);
    }
}

// ---------- pass 1: per-block bucket histogram (cnt[blk*MAXBK + bk]) ----------
__global__ void fa_sort_hist(const int* __restrict__ edst, int* __restrict__ cnt, int E) {
    __shared__ int lh[MAXBK];
    int tid = threadIdx.x;
    for (int i = tid; i < MAXBK; i += blockDim.x) lh[i] = 0;
    __syncthreads();
    int chunk = (E + gridDim.x - 1) / gridDim.x;
    int c0 = blockIdx.x * chunk;
    int c1 = min(E, c0 + chunk);
    for (int i = c0 + tid; i < c1; i += blockDim.x)
        atomicAdd(&lh[edst[i] >> BKSH], 1);
    __syncthreads();
    for (int i = tid; i < MAXBK; i += blockDim.x)
        cnt[blockIdx.x * MAXBK + i] = lh[i];
}

// ---------- scan A: per-bucket exclusive prefix over blocks; bucket totals ----------
__global__ void fa_sort_scanA(int* __restrict__ cnt, int* __restrict__ bktot) {
    __shared__ int sc[SORTB];
    int bk  = blockIdx.x;
    int tid = threadIdx.x;
    int v = cnt[tid * MAXBK + bk];
    sc[tid] = v;
    __syncthreads();
    for (int dd = 1; dd < SORTB; dd <<= 1) {
        int t = (tid >= dd) ? sc[tid - dd] : 0;
        __syncthreads();
        sc[tid] += t;
        __syncthreads();
    }
    cnt[tid * MAXBK + bk] = sc[tid] - v;
    if (tid == SORTB - 1) bktot[bk] = sc[tid];
}

// ---------- scan B: exclusive scan of bucket totals (4 items/thread, 512 thr) ----------
__global__ void fa_sort_scanB(const int* __restrict__ bktot, int* __restrict__ bkoff, int nbk) {
    __shared__ int sc[512];
    int tid = threadIdx.x;
    int base = tid * 4;
    int v[4];
    int s = 0;
    #pragma unroll
    for (int k = 0; k < 4; ++k) {
        int idx = base + k;
        v[k] = (idx < nbk) ? bktot[idx] : 0;
        s += v[k];
    }
    sc[tid] = s;
    __syncthreads();
    for (int dd = 1; dd < 512; dd <<= 1) {
        int t = (tid >= dd) ? sc[tid - dd] : 0;
        __syncthreads();
        sc[tid] += t;
        __syncthreads();
    }
    int run = sc[tid] - s;
    #pragma unroll
    for (int k = 0; k < 4; ++k) {
        int idx = base + k;
        if (idx < nbk) bkoff[idx] = run;
        run += v[k];
    }
}

// ---------- pass 2: place 4-byte record (src<<6 | local_dst); no gate math ----------
__global__ void fa_place(const int* __restrict__ esrc, const int* __restrict__ edst,
                         const int* __restrict__ cnt, const int* __restrict__ bkoff,
                         int* __restrict__ pairs, int E, int nbk) {
    __shared__ int lcur[MAXBK];
    int tid = threadIdx.x;
    for (int i = tid; i < nbk; i += blockDim.x)
        lcur[i] = bkoff[i] + cnt[blockIdx.x * MAXBK + i];
    __syncthreads();
    int chunk = (E + gridDim.x - 1) / gridDim.x;
    int c0 = blockIdx.x * chunk;
    int c1 = min(E, c0 + chunk);
    for (int i = c0 + tid; i < c1; i += blockDim.x) {
        int t = edst[i];
        int s = esrc[i];
        int pos = atomicAdd(&lcur[t >> BKSH], 1);       // LDS atomic
        pairs[pos] = (s << BKSH) | (t & (BKN - 1));
    }
}

// ---------- fused: LDS counting sort + gate compute + wave-per-node gather ----------
__global__ __launch_bounds__(512, 4)
void fa_gather6(const __hip_bfloat16* __restrict__ hb,
                const float2* __restrict__ gdd, const float2* __restrict__ gss,
                const float* __restrict__ gate_b,
                const int* __restrict__ bkoff, const int* __restrict__ bktot,
                const int* __restrict__ pairs,
                float* __restrict__ z, int N) {
    __shared__ int  buf1[CAP];                   // 12 KB (raw records)
    __shared__ int2 buf2[CAP];                   // 24 KB ({src, ev} sorted by node)
    __shared__ float2 gdl[BKN];                  // dst-side {gd, d} for this bucket
    __shared__ int hist[BKN];
    __shared__ int cur[BKN];
    __shared__ int offl[BKN + 1];
    int bk  = blockIdx.x;
    int tid = threadIdx.x;                       // 512 threads = 8 waves
    int s0  = bkoff[bk];
    int c   = bktot[bk];
    int n0  = bk << BKSH;
    int wid  = tid >> 6;
    int lane = tid & 63;
    float gb = gate_b[0];
    if (tid < BKN) {
        int node = n0 + tid;
        gdl[tid]  = (node < N) ? gdd[node] : make_float2(0.f, 0.f);
        hist[tid] = 0;
    }
    __syncthreads();
    if (c <= CAP) {
        for (int i = tid; i < c; i += 512) {
            int r = pairs[s0 + i];
            buf1[i] = r;
            atomicAdd(&hist[r & (BKN - 1)], 1);
        }
        __syncthreads();
        if (tid < BKN) cur[tid] = hist[tid];
        __syncthreads();
        #pragma unroll
        for (int dd = 1; dd < BKN; dd <<= 1) {
            int t = (tid < BKN && tid >= dd) ? cur[tid - dd] : 0;
            __syncthreads();
            if (tid < BKN) cur[tid] += t;
            __syncthreads();
        }
        if (tid < BKN) {
            offl[tid + 1] = cur[tid];            // inclusive -> offl[t+1]
            cur[tid] -= hist[tid];               // exclusive cursor
            if (tid == 0) offl[0] = 0;
        }
        __syncthreads();
        // permute into node-sorted buf2, computing ev on the way
        for (int i = tid; i < c; i += 512) {
            int r  = buf1[i];
            int lt = r & (BKN - 1);
            int s  = r >> BKSH;
            float2 bs = gss[s];
            float2 ad = gdl[lt];
            float g  = fast_tanh(ad.x + bs.x + gb);
            float ev = g * ad.y * bs.y;
            int p = atomicAdd(&cur[lt], 1);
            buf2[p] = make_int2(s, __float_as_int(ev));
        }
        __syncthreads();
        // wave-per-node register gather (proven structure)
        for (int ln = wid; ln < BKN; ln += 8) {
            int node = n0 + ln;
            if (node >= N) break;
            int j   = offl[ln];
            int end = offl[ln + 1];
            float a0 = 0.f, a1 = 0.f, a2 = 0.f, a3 = 0.f;
            for (; j + 4 <= end; j += 4) {
                int2 p0 = buf2[j];
                int2 p1 = buf2[j + 1];
                int2 p2 = buf2[j + 2];
                int2 p3 = buf2[j + 3];
                a0 += __bfloat162float(hb[(size_t)p0.x * DIM + lane]) * __int_as_float(p0.y);
                a1 += __bfloat162float(hb[(size_t)p1.x * DIM + lane]) * __int_as_float(p1.y);
                a2 += __bfloat162float(hb[(size_t)p2.x * DIM + lane]) * __int_as_float(p2.y);
                a3 += __bfloat162float(hb[(size_t)p3.x * DIM + lane]) * __int_as_float(p3.y);
            }
            for (; j < end; ++j) {
                int2 p = buf2[j];
                a0 += __bfloat162float(hb[(size_t)p.x * DIM + lane]) * __int_as_float(p.y);
            }
            z[(size_t)node * DIM + lane] = a0 + a1 + a2 + a3;
        }
    } else {
        // adversarial-skew slow path: filter directly from global (correct, rare)
        for (int ln = wid; ln < BKN; ln += 8) {
            int node = n0 + ln;
            if (node >= N) break;
            float2 ad = gdl[ln];
            float acc = 0.f;
            for (int j = s0; j < s0 + c; ++j) {
                int r = pairs[j];
                if ((r & (BKN - 1)) == ln) {
                    int s = r >> BKSH;
                    float2 bs = gss[s];
                    float g  = fast_tanh(ad.x + bs.x + gb);
                    acc += __bfloat162float(hb[(size_t)s * DIM + lane])
                           * (g * ad.y * bs.y);
                }
            }
            z[(size_t)node * DIM + lane] = acc;
        }
    }
}

// ---------- fallback: atomic scatter ----------
__global__ void fa_edge_scatter_atomic(const float* __restrict__ h,
                                       const float2* __restrict__ gdd,
                                       const float2* __restrict__ gss,
                                       const int* __restrict__ esrc,
                                       const int* __restrict__ edst,
                                       const float* __restrict__ gate_b,
                                       float* __restrict__ z, int E) {
    int gid  = blockIdx.x * blockDim.x + threadIdx.x;
    int edge = gid >> 6;
    int lane = threadIdx.x & 63;
    if (edge >= E) return;
    int s = esrc[edge];
    int t = edst[edge];
    float2 ad = gdd[t];
    float2 bs = gss[s];
    float g  = fast_tanh(ad.x + bs.x + gate_b[0]);
    float ev = g * ad.y * bs.y;
    atomicAdd(&z[(size_t)t * DIM + lane], h[(size_t)s * DIM + lane] * ev);
}

extern "C" void kernel_launch(void* const* d_in, const int* in_sizes, int n_in,
                              void* d_out, int out_size, void* d_ws, size_t ws_size,
                              hipStream_t stream) {
    const float* h      = (const float*)d_in[0];
    const float* dn     = (const float*)d_in[1];
    const float* gate_W = (const float*)d_in[2];
    const float* gate_b = (const float*)d_in[3];
    const int*   esrc   = (const int*)d_in[4];
    const int*   edst   = (const int*)d_in[5];
    float*       z      = (float*)d_out;

    int N = in_sizes[1];
    int E = in_sizes[4];
    int nbk = (N + BKN - 1) >> BKSH;

    // workspace layout
    char* w = (char*)d_ws;
    float2* gdd  = (float2*)w;         w += (size_t)N * 8;
    float2* gss  = (float2*)w;         w += (size_t)N * 8;
    int*   bktot = (int*)w;            w += (size_t)MAXBK * 4;
    int*   bkoff = (int*)w;            w += (size_t)MAXBK * 4;
    int*   cnt   = (int*)w;            w += (size_t)SORTB * MAXBK * 4;  // 3.28 MB
    w = (char*)(((uintptr_t)w + 63) & ~(uintptr_t)63);
    int*  pairs  = (int*)w;            w += ((size_t)E + 64) * 4;
    __hip_bfloat16* hb = (__hip_bfloat16*)w;
    w += (size_t)N * DIM * 2;
    size_t required = (size_t)(w - (char*)d_ws);
    size_t atomic_required = (size_t)N * 16;

    bool use_sort = (ws_size >= required) && (nbk <= MAXBK);

    fa_node_gates<<<(N + 3) / 4, 256, 0, stream>>>(h, gate_W, dn, gdd, gss,
                                                   use_sort ? hb : (__hip_bfloat16*)nullptr, N);

    if (use_sort) {
        fa_sort_hist<<<SORTB, SORTT, 0, stream>>>(edst, cnt, E);
        fa_sort_scanA<<<nbk, SORTB, 0, stream>>>(cnt, bktot);
        fa_sort_scanB<<<1, 512, 0, stream>>>(bktot, bkoff, nbk);
        fa_place<<<SORTB, SORTT, 0, stream>>>(esrc, edst, cnt, bkoff, pairs, E, nbk);
        fa_gather6<<<nbk, 512, 0, stream>>>(hb, gdd, gss, gate_b, bkoff, bktot,
                                            pairs, z, N);
    } else if (ws_size >= atomic_required) {
        hipMemsetAsync(z, 0, (size_t)out_size * sizeof(float), stream);
        fa_edge_scatter_atomic<<<(E + 3) / 4, 256, 0, stream>>>(h, gdd, gss, esrc,
                                                                edst, gate_b, z, E);
    }
}

// Round 12
// 141.500 us; speedup vs baseline: 2.1133x; 1.2702x over previous
//
#include <hip/hip_runtime.h>
#include <hip/hip_bf16.h>

#define DIM 64
#define BKN 64               // nodes per bucket
#define BKSH 6               // log2(BKN)
#define MAXBK 1600           // supports N <= 102400
#define SORTB 256            // blocks for hist/place (8 recs/bucket/block -> ~2x ampl)
#define SORTT 512            // threads per hist/place block
#define CAP 3072             // fused-gather LDS record capacity; mean ~2048

__device__ inline float fast_tanh(float x) {
    float e = __expf(2.0f * x);
    return 1.0f - 2.0f / (e + 1.0f);
}

// ---------- fused: hist role (blocks [0,HB)) + gates role (rest) ----------
__global__ void fa_gates_hist(const float* __restrict__ h,
                              const float* __restrict__ gate_W,
                              const float* __restrict__ dn,
                              float2* __restrict__ gdd,
                              float2* __restrict__ gss,
                              __hip_bfloat16* __restrict__ hb,
                              const int* __restrict__ edst,
                              int* __restrict__ cnt,
                              int E, int N, int histBlocks) {
    __shared__ int lh[MAXBK];
    int tid = threadIdx.x;                        // 512 threads
    if ((int)blockIdx.x < histBlocks) {
        // -------- histogram role --------
        for (int i = tid; i < MAXBK; i += 512) lh[i] = 0;
        __syncthreads();
        int chunk = (E + histBlocks - 1) / histBlocks;
        int c0 = blockIdx.x * chunk;
        int c1 = min(E, c0 + chunk);
        for (int i = c0 + tid; i < c1; i += 512)
            atomicAdd(&lh[edst[i] >> BKSH], 1);
        __syncthreads();
        for (int i = tid; i < MAXBK; i += 512)
            cnt[blockIdx.x * MAXBK + i] = lh[i];
    } else {
        // -------- gates role: 8 nodes per block --------
        int gid  = (blockIdx.x - histBlocks) * 512 + tid;
        int node = gid >> 6;
        int lane = tid & 63;
        if (node >= N) return;
        float x = h[(size_t)node * DIM + lane];
        hb[(size_t)node * DIM + lane] = __float2bfloat16(x);
        float a = x * gate_W[lane];
        float b = x * gate_W[DIM + lane];
        #pragma unroll
        for (int off = 32; off >= 1; off >>= 1) {
            a += __shfl_xor(a, off, 64);
            b += __shfl_xor(b, off, 64);
        }
        if (lane == 0) {
            float dv = dn[node];
            gdd[node] = make_float2(a, dv);
            gss[node] = make_float2(b, dv);
        }
    }
}

// ---------- standalone gates (fallback path only) ----------
__global__ void fa_node_gates(const float* __restrict__ h,
                              const float* __restrict__ gate_W,
                              const float* __restrict__ dn,
                              float2* __restrict__ gdd,
                              float2* __restrict__ gss,
                              int N) {
    int gid  = blockIdx.x * blockDim.x + threadIdx.x;
    int node = gid >> 6;
    int lane = threadIdx.x & 63;
    if (node >= N) return;
    float x = h[(size_t)node * DIM + lane];
    float a = x * gate_W[lane];
    float b = x * gate_W[DIM + lane];
    #pragma unroll
    for (int off = 32; off >= 1; off >>= 1) {
        a += __shfl_xor(a, off, 64);
        b += __shfl_xor(b, off, 64);
    }
    if (lane == 0) {
        float dv = dn[node];
        gdd[node] = make_float2(a, dv);
        gss[node] = make_float2(b, dv);
    }
}

// ---------- scan A: per-bucket exclusive prefix over SORTB blocks ----------
__global__ void fa_sort_scanA(int* __restrict__ cnt, int* __restrict__ bktot) {
    __shared__ int sc[SORTB];
    int bk  = blockIdx.x;
    int tid = threadIdx.x;                        // SORTB threads
    int v = cnt[tid * MAXBK + bk];
    sc[tid] = v;
    __syncthreads();
    for (int dd = 1; dd < SORTB; dd <<= 1) {
        int t = (tid >= dd) ? sc[tid - dd] : 0;
        __syncthreads();
        sc[tid] += t;
        __syncthreads();
    }
    cnt[tid * MAXBK + bk] = sc[tid] - v;
    if (tid == SORTB - 1) bktot[bk] = sc[tid];
}

// ---------- scan B: exclusive scan of bucket totals (4 items/thread, 512 thr) ----------
__global__ void fa_sort_scanB(const int* __restrict__ bktot, int* __restrict__ bkoff, int nbk) {
    __shared__ int sc[512];
    int tid = threadIdx.x;
    int base = tid * 4;
    int v[4];
    int s = 0;
    #pragma unroll
    for (int k = 0; k < 4; ++k) {
        int idx = base + k;
        v[k] = (idx < nbk) ? bktot[idx] : 0;
        s += v[k];
    }
    sc[tid] = s;
    __syncthreads();
    for (int dd = 1; dd < 512; dd <<= 1) {
        int t = (tid >= dd) ? sc[tid - dd] : 0;
        __syncthreads();
        sc[tid] += t;
        __syncthreads();
    }
    int run = sc[tid] - s;
    #pragma unroll
    for (int k = 0; k < 4; ++k) {
        int idx = base + k;
        if (idx < nbk) bkoff[idx] = run;
        run += v[k];
    }
}

// ---------- place 4-byte record (src<<6 | local_dst); no gate math ----------
__global__ void fa_place(const int* __restrict__ esrc, const int* __restrict__ edst,
                         const int* __restrict__ cnt, const int* __restrict__ bkoff,
                         int* __restrict__ pairs, int E, int nbk) {
    __shared__ int lcur[MAXBK];
    int tid = threadIdx.x;
    for (int i = tid; i < nbk; i += blockDim.x)
        lcur[i] = bkoff[i] + cnt[blockIdx.x * MAXBK + i];
    __syncthreads();
    int chunk = (E + gridDim.x - 1) / gridDim.x;
    int c0 = blockIdx.x * chunk;
    int c1 = min(E, c0 + chunk);
    for (int i = c0 + tid; i < c1; i += blockDim.x) {
        int t = edst[i];
        int s = esrc[i];
        int pos = atomicAdd(&lcur[t >> BKSH], 1);       // LDS atomic
        pairs[pos] = (s << BKSH) | (t & (BKN - 1));
    }
}

// ---------- fused: LDS counting sort + gate compute + half-wave-pair gather ----------
__global__ __launch_bounds__(512, 4)
void fa_gather7(const __hip_bfloat16* __restrict__ hb,
                const float2* __restrict__ gdd, const float2* __restrict__ gss,
                const float* __restrict__ gate_b,
                const int* __restrict__ bkoff, const int* __restrict__ bktot,
                const int* __restrict__ pairs,
                float* __restrict__ z, int N) {
    __shared__ int  buf1[CAP];                   // 12 KB (raw records)
    __shared__ int2 buf2[CAP];                   // 24 KB ({src, ev} sorted by node)
    __shared__ float2 gdl[BKN];                  // dst-side {gd, d} for this bucket
    __shared__ int hist[BKN];
    __shared__ int cur[BKN];
    __shared__ int offl[BKN + 1];
    int bk  = blockIdx.x;
    int tid = threadIdx.x;                       // 512 threads = 8 waves
    int s0  = bkoff[bk];
    int c   = bktot[bk];
    int n0  = bk << BKSH;
    int wid  = tid >> 6;
    int lane = tid & 63;
    float gb = gate_b[0];
    if (tid < BKN) {
        int node = n0 + tid;
        gdl[tid]  = (node < N) ? gdd[node] : make_float2(0.f, 0.f);
        hist[tid] = 0;
    }
    __syncthreads();
    if (c <= CAP) {
        for (int i = tid; i < c; i += 512) {
            int r = pairs[s0 + i];
            buf1[i] = r;
            atomicAdd(&hist[r & (BKN - 1)], 1);
        }
        __syncthreads();
        if (tid < BKN) cur[tid] = hist[tid];
        __syncthreads();
        #pragma unroll
        for (int dd = 1; dd < BKN; dd <<= 1) {
            int t = (tid < BKN && tid >= dd) ? cur[tid - dd] : 0;
            __syncthreads();
            if (tid < BKN) cur[tid] += t;
            __syncthreads();
        }
        if (tid < BKN) {
            offl[tid + 1] = cur[tid];            // inclusive -> offl[t+1]
            cur[tid] -= hist[tid];               // exclusive cursor
            if (tid == 0) offl[0] = 0;
        }
        __syncthreads();
        // permute into node-sorted buf2, computing ev on the way
        for (int i = tid; i < c; i += 512) {
            int r  = buf1[i];
            int lt = r & (BKN - 1);
            int s  = r >> BKSH;
            float2 bs = gss[s];
            float2 ad = gdl[lt];
            float g  = fast_tanh(ad.x + bs.x + gb);
            float ev = g * ad.y * bs.y;
            int p = atomicAdd(&cur[lt], 1);
            buf2[p] = make_int2(s, __float_as_int(ev));
        }
        __syncthreads();
        // half-wave-pair gather: each 32-lane half owns alternate records,
        // lane handles 2 dims (4-B load per record per lane)
        int half = lane >> 5;                    // 0: even records, 1: odd
        int l32  = lane & 31;
        for (int ln = wid; ln < BKN; ln += 8) {
            int node = n0 + ln;
            if (node >= N) break;
            int jb  = offl[ln];
            int end = offl[ln + 1];
            float ax = 0.f, ay = 0.f, bx = 0.f, by = 0.f;
            float cx = 0.f, cy = 0.f, dx = 0.f, dy = 0.f;
            int j = jb + half;
            for (; j + 6 < end; j += 8) {        // 4 records per half in flight
                int2 p0 = buf2[j];
                int2 p1 = buf2[j + 2];
                int2 p2 = buf2[j + 4];
                int2 p3 = buf2[j + 6];
                uint q0 = ((const uint*)(hb + (size_t)p0.x * DIM))[l32];
                uint q1 = ((const uint*)(hb + (size_t)p1.x * DIM))[l32];
                uint q2 = ((const uint*)(hb + (size_t)p2.x * DIM))[l32];
                uint q3 = ((const uint*)(hb + (size_t)p3.x * DIM))[l32];
                float e0 = __int_as_float(p0.y);
                float e1 = __int_as_float(p1.y);
                float e2 = __int_as_float(p2.y);
                float e3 = __int_as_float(p3.y);
                ax += __uint_as_float(q0 << 16) * e0;
                ay += __uint_as_float(q0 & 0xffff0000u) * e0;
                bx += __uint_as_float(q1 << 16) * e1;
                by += __uint_as_float(q1 & 0xffff0000u) * e1;
                cx += __uint_as_float(q2 << 16) * e2;
                cy += __uint_as_float(q2 & 0xffff0000u) * e2;
                dx += __uint_as_float(q3 << 16) * e3;
                dy += __uint_as_float(q3 & 0xffff0000u) * e3;
            }
            for (; j < end; j += 2) {            // tail: 1 record per half
                int2 p = buf2[j];
                uint q = ((const uint*)(hb + (size_t)p.x * DIM))[l32];
                float e = __int_as_float(p.y);
                ax += __uint_as_float(q << 16) * e;
                ay += __uint_as_float(q & 0xffff0000u) * e;
            }
            float zx = ax + bx + cx + dx;
            float zy = ay + by + cy + dy;
            zx += __shfl_xor(zx, 32, 64);
            zy += __shfl_xor(zy, 32, 64);
            if (half == 0)
                *(float2*)&z[(size_t)node * DIM + (l32 << 1)] = make_float2(zx, zy);
        }
    } else {
        // adversarial-skew slow path: filter directly from global (correct, rare)
        for (int ln = wid; ln < BKN; ln += 8) {
            int node = n0 + ln;
            if (node >= N) break;
            float2 ad = gdl[ln];
            float acc = 0.f;
            for (int j = s0; j < s0 + c; ++j) {
                int r = pairs[j];
                if ((r & (BKN - 1)) == ln) {
                    int s = r >> BKSH;
                    float2 bs = gss[s];
                    float g  = fast_tanh(ad.x + bs.x + gb);
                    acc += __bfloat162float(hb[(size_t)s * DIM + lane])
                           * (g * ad.y * bs.y);
                }
            }
            z[(size_t)node * DIM + lane] = acc;
        }
    }
}

// ---------- fallback: atomic scatter ----------
__global__ void fa_edge_scatter_atomic(const float* __restrict__ h,
                                       const float2* __restrict__ gdd,
                                       const float2* __restrict__ gss,
                                       const int* __restrict__ esrc,
                                       const int* __restrict__ edst,
                                       const float* __restrict__ gate_b,
                                       float* __restrict__ z, int E) {
    int gid  = blockIdx.x * blockDim.x + threadIdx.x;
    int edge = gid >> 6;
    int lane = threadIdx.x & 63;
    if (edge >= E) return;
    int s = esrc[edge];
    int t = edst[edge];
    float2 ad = gdd[t];
    float2 bs = gss[s];
    float g  = fast_tanh(ad.x + bs.x + gate_b[0]);
    float ev = g * ad.y * bs.y;
    atomicAdd(&z[(size_t)t * DIM + lane], h[(size_t)s * DIM + lane] * ev);
}

extern "C" void kernel_launch(void* const* d_in, const int* in_sizes, int n_in,
                              void* d_out, int out_size, void* d_ws, size_t ws_size,
                              hipStream_t stream) {
    const float* h      = (const float*)d_in[0];
    const float* dn     = (const float*)d_in[1];
    const float* gate_W = (const float*)d_in[2];
    const float* gate_b = (const float*)d_in[3];
    const int*   esrc   = (const int*)d_in[4];
    const int*   edst   = (const int*)d_in[5];
    float*       z      = (float*)d_out;

    int N = in_sizes[1];
    int E = in_sizes[4];
    int nbk = (N + BKN - 1) >> BKSH;

    // workspace layout
    char* w = (char*)d_ws;
    float2* gdd  = (float2*)w;         w += (size_t)N * 8;
    float2* gss  = (float2*)w;         w += (size_t)N * 8;
    int*   bktot = (int*)w;            w += (size_t)MAXBK * 4;
    int*   bkoff = (int*)w;            w += (size_t)MAXBK * 4;
    int*   cnt   = (int*)w;            w += (size_t)SORTB * MAXBK * 4;  // 1.64 MB
    w = (char*)(((uintptr_t)w + 63) & ~(uintptr_t)63);
    int*  pairs  = (int*)w;            w += ((size_t)E + 64) * 4;
    __hip_bfloat16* hb = (__hip_bfloat16*)w;
    w += (size_t)N * DIM * 2;
    size_t required = (size_t)(w - (char*)d_ws);
    size_t atomic_required = (size_t)N * 16;

    bool use_sort = (ws_size >= required) && (nbk <= MAXBK);

    if (use_sort) {
        int gatesBlocks = (N + 7) / 8;           // 512 thr = 8 nodes/block
        fa_gates_hist<<<SORTB + gatesBlocks, 512, 0, stream>>>(
            h, gate_W, dn, gdd, gss, hb, edst, cnt, E, N, SORTB);
        fa_sort_scanA<<<nbk, SORTB, 0, stream>>>(cnt, bktot);
        fa_sort_scanB<<<1, 512, 0, stream>>>(bktot, bkoff, nbk);
        fa_place<<<SORTB, SORTT, 0, stream>>>(esrc, edst, cnt, bkoff, pairs, E, nbk);
        fa_gather7<<<nbk, 512, 0, stream>>>(hb, gdd, gss, gate_b, bkoff, bktot,
                                            pairs, z, N);
    } else if (ws_size >= atomic_required) {
        fa_node_gates<<<(N + 3) / 4, 256, 0, stream>>>(h, gate_W, dn, gdd, gss, N);
        hipMemsetAsync(z, 0, (size_t)out_size * sizeof(float), stream);
        fa_edge_scatter_atomic<<<(E + 3) / 4, 256, 0, stream>>>(h, gdd, gss, esrc,
                                                                edst, gate_b, z, E);
    }
}

// Round 13
// 140.233 us; speedup vs baseline: 2.1324x; 1.0090x over previous
//
#include <hip/hip_runtime.h>
#include <hip/hip_bf16.h>

#define DIM 64
#define BKN 64               // nodes per bucket
#define BKSH 6               // log2(BKN)
#define MAXBK 1600           // supports N <= 102400
#define SORTB 256            // blocks for hist/place (8 recs/bucket/block -> ~2x ampl)
#define SORTT 512            // threads for gates_hist
#define PLACET 1024          // threads for place
#define CAP 4096             // fused-gather LDS record capacity; mean ~2048

__device__ inline float fast_tanh(float x) {
    float e = __expf(2.0f * x);
    return 1.0f - 2.0f / (e + 1.0f);
}

// ---------- fused: hist role (blocks [0,HB)) + gates role (rest) ----------
__global__ void fa_gates_hist(const float* __restrict__ h,
                              const float* __restrict__ gate_W,
                              const float* __restrict__ dn,
                              float2* __restrict__ gdd,
                              float2* __restrict__ gss,
                              __hip_bfloat16* __restrict__ hb,
                              const int* __restrict__ edst,
                              int* __restrict__ cnt,
                              int E, int N, int histBlocks) {
    __shared__ int lh[MAXBK];
    int tid = threadIdx.x;                        // 512 threads
    if ((int)blockIdx.x < histBlocks) {
        // -------- histogram role --------
        for (int i = tid; i < MAXBK; i += 512) lh[i] = 0;
        __syncthreads();
        int chunk = (E + histBlocks - 1) / histBlocks;
        int c0 = blockIdx.x * chunk;
        int c1 = min(E, c0 + chunk);
        for (int i = c0 + tid; i < c1; i += 512)
            atomicAdd(&lh[edst[i] >> BKSH], 1);
        __syncthreads();
        for (int i = tid; i < MAXBK; i += 512)
            cnt[blockIdx.x * MAXBK + i] = lh[i];
    } else {
        // -------- gates role: 8 nodes per block --------
        int gid  = (blockIdx.x - histBlocks) * 512 + tid;
        int node = gid >> 6;
        int lane = tid & 63;
        if (node >= N) return;
        float x = h[(size_t)node * DIM + lane];
        hb[(size_t)node * DIM + lane] = __float2bfloat16(x);
        float a = x * gate_W[lane];
        float b = x * gate_W[DIM + lane];
        #pragma unroll
        for (int off = 32; off >= 1; off >>= 1) {
            a += __shfl_xor(a, off, 64);
            b += __shfl_xor(b, off, 64);
        }
        if (lane == 0) {
            float dv = dn[node];
            gdd[node] = make_float2(a, dv);
            gss[node] = make_float2(b, dv);
        }
    }
}

// ---------- standalone gates (fallback path only) ----------
__global__ void fa_node_gates(const float* __restrict__ h,
                              const float* __restrict__ gate_W,
                              const float* __restrict__ dn,
                              float2* __restrict__ gdd,
                              float2* __restrict__ gss,
                              int N) {
    int gid  = blockIdx.x * blockDim.x + threadIdx.x;
    int node = gid >> 6;
    int lane = threadIdx.x & 63;
    if (node >= N) return;
    float x = h[(size_t)node * DIM + lane];
    float a = x * gate_W[lane];
    float b = x * gate_W[DIM + lane];
    #pragma unroll
    for (int off = 32; off >= 1; off >>= 1) {
        a += __shfl_xor(a, off, 64);
        b += __shfl_xor(b, off, 64);
    }
    if (lane == 0) {
        float dv = dn[node];
        gdd[node] = make_float2(a, dv);
        gss[node] = make_float2(b, dv);
    }
}

// ---------- scan A: per-bucket exclusive prefix over SORTB blocks ----------
__global__ void fa_sort_scanA(int* __restrict__ cnt, int* __restrict__ bktot) {
    __shared__ int sc[SORTB];
    int bk  = blockIdx.x;
    int tid = threadIdx.x;                        // SORTB threads
    int v = cnt[tid * MAXBK + bk];
    sc[tid] = v;
    __syncthreads();
    for (int dd = 1; dd < SORTB; dd <<= 1) {
        int t = (tid >= dd) ? sc[tid - dd] : 0;
        __syncthreads();
        sc[tid] += t;
        __syncthreads();
    }
    cnt[tid * MAXBK + bk] = sc[tid] - v;
    if (tid == SORTB - 1) bktot[bk] = sc[tid];
}

// ---------- scan B: exclusive scan of bucket totals (4 items/thread, 512 thr) ----------
__global__ void fa_sort_scanB(const int* __restrict__ bktot, int* __restrict__ bkoff, int nbk) {
    __shared__ int sc[512];
    int tid = threadIdx.x;
    int base = tid * 4;
    int v[4];
    int s = 0;
    #pragma unroll
    for (int k = 0; k < 4; ++k) {
        int idx = base + k;
        v[k] = (idx < nbk) ? bktot[idx] : 0;
        s += v[k];
    }
    sc[tid] = s;
    __syncthreads();
    for (int dd = 1; dd < 512; dd <<= 1) {
        int t = (tid >= dd) ? sc[tid - dd] : 0;
        __syncthreads();
        sc[tid] += t;
        __syncthreads();
    }
    int run = sc[tid] - s;
    #pragma unroll
    for (int k = 0; k < 4; ++k) {
        int idx = base + k;
        if (idx < nbk) bkoff[idx] = run;
        run += v[k];
    }
}

// ---------- place 4-byte record (src<<6 | local_dst); no gate math ----------
__global__ void fa_place(const int* __restrict__ esrc, const int* __restrict__ edst,
                         const int* __restrict__ cnt, const int* __restrict__ bkoff,
                         int* __restrict__ pairs, int E, int nbk) {
    __shared__ int lcur[MAXBK];
    int tid = threadIdx.x;                        // PLACET threads
    for (int i = tid; i < nbk; i += blockDim.x)
        lcur[i] = bkoff[i] + cnt[blockIdx.x * MAXBK + i];
    __syncthreads();
    int chunk = (E + gridDim.x - 1) / gridDim.x;
    int c0 = blockIdx.x * chunk;
    int c1 = min(E, c0 + chunk);
    for (int i = c0 + tid; i < c1; i += blockDim.x) {
        int t = edst[i];
        int s = esrc[i];
        int pos = atomicAdd(&lcur[t >> BKSH], 1);       // LDS atomic
        pairs[pos] = (s << BKSH) | (t & (BKN - 1));
    }
}

__device__ inline float4 bf16x4_unpack(uint2 q) {
    return make_float4(__uint_as_float(q.x << 16),
                       __uint_as_float(q.x & 0xffff0000u),
                       __uint_as_float(q.y << 16),
                       __uint_as_float(q.y & 0xffff0000u));
}

// ---------- fused: LDS counting sort + gate compute + quarter-wave gather ----------
__global__ __launch_bounds__(512, 4)
void fa_gather8(const __hip_bfloat16* __restrict__ hb,
                const float2* __restrict__ gdd, const float2* __restrict__ gss,
                const float* __restrict__ gate_b,
                const int* __restrict__ bkoff, const int* __restrict__ bktot,
                const int* __restrict__ pairs,
                float* __restrict__ z, int N) {
    __shared__ int2 buf2[CAP];                   // 32 KB ({src, ev} sorted by node)
    __shared__ float2 gdl[BKN];                  // dst-side {gd, d} for this bucket
    __shared__ int hist[BKN];
    __shared__ int cur[BKN];
    __shared__ int offl[BKN + 1];
    int bk  = blockIdx.x;
    int tid = threadIdx.x;                       // 512 threads = 8 waves
    int s0  = bkoff[bk];
    int c   = bktot[bk];
    int n0  = bk << BKSH;
    int wid  = tid >> 6;
    int lane = tid & 63;
    float gb = gate_b[0];
    if (tid < BKN) {
        int node = n0 + tid;
        gdl[tid]  = (node < N) ? gdd[node] : make_float2(0.f, 0.f);
        hist[tid] = 0;
    }
    __syncthreads();
    if (c <= CAP) {
        // pass 1: histogram from global pairs
        for (int i = tid; i < c; i += 512)
            atomicAdd(&hist[pairs[s0 + i] & (BKN - 1)], 1);
        __syncthreads();
        if (tid < BKN) cur[tid] = hist[tid];
        __syncthreads();
        #pragma unroll
        for (int dd = 1; dd < BKN; dd <<= 1) {
            int t = (tid < BKN && tid >= dd) ? cur[tid - dd] : 0;
            __syncthreads();
            if (tid < BKN) cur[tid] += t;
            __syncthreads();
        }
        if (tid < BKN) {
            offl[tid + 1] = cur[tid];            // inclusive -> offl[t+1]
            cur[tid] -= hist[tid];               // exclusive cursor
            if (tid == 0) offl[0] = 0;
        }
        __syncthreads();
        // pass 2: permute into node-sorted buf2 (pairs now L2-hot), ev on the way
        for (int i = tid; i < c; i += 512) {
            int r  = pairs[s0 + i];
            int lt = r & (BKN - 1);
            int s  = r >> BKSH;
            float2 bs = gss[s];
            float2 ad = gdl[lt];
            float g  = fast_tanh(ad.x + bs.x + gb);
            float ev = g * ad.y * bs.y;
            int p = atomicAdd(&cur[lt], 1);
            buf2[p] = make_int2(s, __float_as_int(ev));
        }
        __syncthreads();
        // quarter-wave gather: 16 lanes per record (4 dims/lane), 4 quarters,
        // 4-deep unroll -> 16 records in flight per wave
        int qid = lane >> 4;                     // quarter 0..3
        int l16 = lane & 15;
        for (int ln = wid; ln < BKN; ln += 8) {
            int node = n0 + ln;
            if (node >= N) break;
            int j   = offl[ln];
            int end = offl[ln + 1];
            float4 a0 = make_float4(0.f, 0.f, 0.f, 0.f);
            float4 a1 = a0, a2 = a0, a3 = a0;
            for (; j + 16 <= end; j += 16) {
                int2 p0 = buf2[j + qid];
                int2 p1 = buf2[j + qid + 4];
                int2 p2 = buf2[j + qid + 8];
                int2 p3 = buf2[j + qid + 12];
                uint2 q0 = ((const uint2*)(hb + (size_t)p0.x * DIM))[l16];
                uint2 q1 = ((const uint2*)(hb + (size_t)p1.x * DIM))[l16];
                uint2 q2 = ((const uint2*)(hb + (size_t)p2.x * DIM))[l16];
                uint2 q3 = ((const uint2*)(hb + (size_t)p3.x * DIM))[l16];
                float e0 = __int_as_float(p0.y);
                float e1 = __int_as_float(p1.y);
                float e2 = __int_as_float(p2.y);
                float e3 = __int_as_float(p3.y);
                float4 h0 = bf16x4_unpack(q0);
                float4 h1 = bf16x4_unpack(q1);
                float4 h2 = bf16x4_unpack(q2);
                float4 h3 = bf16x4_unpack(q3);
                a0.x += h0.x * e0; a0.y += h0.y * e0; a0.z += h0.z * e0; a0.w += h0.w * e0;
                a1.x += h1.x * e1; a1.y += h1.y * e1; a1.z += h1.z * e1; a1.w += h1.w * e1;
                a2.x += h2.x * e2; a2.y += h2.y * e2; a2.z += h2.z * e2; a2.w += h2.w * e2;
                a3.x += h3.x * e3; a3.y += h3.y * e3; a3.z += h3.z * e3; a3.w += h3.w * e3;
            }
            for (; j + 4 <= end; j += 4) {
                int2 p = buf2[j + qid];
                uint2 q = ((const uint2*)(hb + (size_t)p.x * DIM))[l16];
                float e = __int_as_float(p.y);
                float4 hv = bf16x4_unpack(q);
                a0.x += hv.x * e; a0.y += hv.y * e; a0.z += hv.z * e; a0.w += hv.w * e;
            }
            int rem = end - j;
            if (rem > 0) {
                int idx = j + (qid < rem ? qid : 0);
                int2 p = buf2[idx];
                float e = (qid < rem) ? __int_as_float(p.y) : 0.f;
                uint2 q = ((const uint2*)(hb + (size_t)p.x * DIM))[l16];
                float4 hv = bf16x4_unpack(q);
                a0.x += hv.x * e; a0.y += hv.y * e; a0.z += hv.z * e; a0.w += hv.w * e;
            }
            float4 t;
            t.x = a0.x + a1.x + a2.x + a3.x;
            t.y = a0.y + a1.y + a2.y + a3.y;
            t.z = a0.z + a1.z + a2.z + a3.z;
            t.w = a0.w + a1.w + a2.w + a3.w;
            t.x += __shfl_xor(t.x, 16, 64);  t.x += __shfl_xor(t.x, 32, 64);
            t.y += __shfl_xor(t.y, 16, 64);  t.y += __shfl_xor(t.y, 32, 64);
            t.z += __shfl_xor(t.z, 16, 64);  t.z += __shfl_xor(t.z, 32, 64);
            t.w += __shfl_xor(t.w, 16, 64);  t.w += __shfl_xor(t.w, 32, 64);
            if (qid == 0)
                *(float4*)&z[(size_t)node * DIM + (l16 << 2)] = t;
        }
    } else {
        // adversarial-skew slow path: filter directly from global (correct, rare)
        for (int ln = wid; ln < BKN; ln += 8) {
            int node = n0 + ln;
            if (node >= N) break;
            float2 ad = gdl[ln];
            float acc = 0.f;
            for (int j = s0; j < s0 + c; ++j) {
                int r = pairs[j];
                if ((r & (BKN - 1)) == ln) {
                    int s = r >> BKSH;
                    float2 bs = gss[s];
                    float g  = fast_tanh(ad.x + bs.x + gb);
                    acc += __bfloat162float(hb[(size_t)s * DIM + lane])
                           * (g * ad.y * bs.y);
                }
            }
            z[(size_t)node * DIM + lane] = acc;
        }
    }
}

// ---------- fallback: atomic scatter ----------
__global__ void fa_edge_scatter_atomic(const float* __restrict__ h,
                                       const float2* __restrict__ gdd,
                                       const float2* __restrict__ gss,
                                       const int* __restrict__ esrc,
                                       const int* __restrict__ edst,
                                       const float* __restrict__ gate_b,
                                       float* __restrict__ z, int E) {
    int gid  = blockIdx.x * blockDim.x + threadIdx.x;
    int edge = gid >> 6;
    int lane = threadIdx.x & 63;
    if (edge >= E) return;
    int s = esrc[edge];
    int t = edst[edge];
    float2 ad = gdd[t];
    float2 bs = gss[s];
    float g  = fast_tanh(ad.x + bs.x + gate_b[0]);
    float ev = g * ad.y * bs.y;
    atomicAdd(&z[(size_t)t * DIM + lane], h[(size_t)s * DIM + lane] * ev);
}

extern "C" void kernel_launch(void* const* d_in, const int* in_sizes, int n_in,
                              void* d_out, int out_size, void* d_ws, size_t ws_size,
                              hipStream_t stream) {
    const float* h      = (const float*)d_in[0];
    const float* dn     = (const float*)d_in[1];
    const float* gate_W = (const float*)d_in[2];
    const float* gate_b = (const float*)d_in[3];
    const int*   esrc   = (const int*)d_in[4];
    const int*   edst   = (const int*)d_in[5];
    float*       z      = (float*)d_out;

    int N = in_sizes[1];
    int E = in_sizes[4];
    int nbk = (N + BKN - 1) >> BKSH;

    // workspace layout
    char* w = (char*)d_ws;
    float2* gdd  = (float2*)w;         w += (size_t)N * 8;
    float2* gss  = (float2*)w;         w += (size_t)N * 8;
    int*   bktot = (int*)w;            w += (size_t)MAXBK * 4;
    int*   bkoff = (int*)w;            w += (size_t)MAXBK * 4;
    int*   cnt   = (int*)w;            w += (size_t)SORTB * MAXBK * 4;  // 1.64 MB
    w = (char*)(((uintptr_t)w + 63) & ~(uintptr_t)63);
    int*  pairs  = (int*)w;            w += ((size_t)E + 64) * 4;
    __hip_bfloat16* hb = (__hip_bfloat16*)w;
    w += (size_t)N * DIM * 2;
    size_t required = (size_t)(w - (char*)d_ws);
    size_t atomic_required = (size_t)N * 16;

    bool use_sort = (ws_size >= required) && (nbk <= MAXBK);

    if (use_sort) {
        int gatesBlocks = (N + 7) / 8;           // 512 thr = 8 nodes/block
        fa_gates_hist<<<SORTB + gatesBlocks, 512, 0, stream>>>(
            h, gate_W, dn, gdd, gss, hb, edst, cnt, E, N, SORTB);
        fa_sort_scanA<<<nbk, SORTB, 0, stream>>>(cnt, bktot);
        fa_sort_scanB<<<1, 512, 0, stream>>>(bktot, bkoff, nbk);
        fa_place<<<SORTB, PLACET, 0, stream>>>(esrc, edst, cnt, bkoff, pairs, E, nbk);
        fa_gather8<<<nbk, 512, 0, stream>>>(hb, gdd, gss, gate_b, bkoff, bktot,
                                            pairs, z, N);
    } else if (ws_size >= atomic_required) {
        fa_node_gates<<<(N + 3) / 4, 256, 0, stream>>>(h, gate_W, dn, gdd, gss, N);
        hipMemsetAsync(z, 0, (size_t)out_size * sizeof(float), stream);
        fa_edge_scatter_atomic<<<(E + 3) / 4, 256, 0, stream>>>(h, gdd, gss, esrc,
                                                                edst, gate_b, z, E);
    }
}

// Round 14
// 137.011 us; speedup vs baseline: 2.1826x; 1.0235x over previous
//
#include <hip/hip_runtime.h>
#include <hip/hip_bf16.h>

#define DIM 64
#define BKN 64               // nodes per bucket
#define BKSH 6               // log2(BKN)
#define MAXBK 1600           // supports N <= 102400
#define SORTB 256            // blocks for hist/place
#define SORTT 512            // threads for gates_hist
#define PLACET 1024          // threads for place
#define CAP 4096             // fused-gather LDS record capacity; mean ~2048

__device__ inline float fast_tanh(float x) {
    float e = __expf(2.0f * x);
    return 1.0f - 2.0f / (e + 1.0f);
}

__device__ inline float4 i8x4_unpack(uint q) {
    return make_float4((float)((int)(q << 24) >> 24),
                       (float)((int)(q << 16) >> 24),
                       (float)((int)(q <<  8) >> 24),
                       (float)((int)q >> 24));
}

// ---------- fused: hist role (blocks [0,HB)) + gates/quant role (rest) ----------
__global__ void fa_gates_hist(const float* __restrict__ h,
                              const float* __restrict__ gate_W,
                              const float* __restrict__ dn,
                              float2* __restrict__ gdd,
                              float4* __restrict__ gss4,
                              unsigned char* __restrict__ hq,
                              const int* __restrict__ edst,
                              int* __restrict__ cnt,
                              int E, int N, int histBlocks) {
    __shared__ int lh[MAXBK];
    int tid = threadIdx.x;                        // 512 threads
    if ((int)blockIdx.x < histBlocks) {
        // -------- histogram role --------
        for (int i = tid; i < MAXBK; i += 512) lh[i] = 0;
        __syncthreads();
        int chunk = (E + histBlocks - 1) / histBlocks;
        int c0 = blockIdx.x * chunk;
        int c1 = min(E, c0 + chunk);
        for (int i = c0 + tid; i < c1; i += 512)
            atomicAdd(&lh[edst[i] >> BKSH], 1);
        __syncthreads();
        for (int i = tid; i < MAXBK; i += 512)
            cnt[blockIdx.x * MAXBK + i] = lh[i];
    } else {
        // -------- gates + int8 quantization role: 8 nodes per block --------
        int gid  = (blockIdx.x - histBlocks) * 512 + tid;
        int node = gid >> 6;
        int lane = tid & 63;
        if (node >= N) return;
        float x = h[(size_t)node * DIM + lane];
        float a = x * gate_W[lane];
        float b = x * gate_W[DIM + lane];
        float m = fabsf(x);
        #pragma unroll
        for (int off = 32; off >= 1; off >>= 1) {
            a += __shfl_xor(a, off, 64);
            b += __shfl_xor(b, off, 64);
            m = fmaxf(m, __shfl_xor(m, off, 64));
        }
        float inv = (m > 0.f) ? (127.0f / m) : 0.f;
        int q = __float2int_rn(x * inv);
        int s0 = __shfl(q, (lane << 2) + 0, 64);
        int s1 = __shfl(q, (lane << 2) + 1, 64);
        int s2 = __shfl(q, (lane << 2) + 2, 64);
        int s3 = __shfl(q, (lane << 2) + 3, 64);
        if (lane < 16) {
            uint packed = (uint)(s0 & 0xff) | ((uint)(s1 & 0xff) << 8)
                        | ((uint)(s2 & 0xff) << 16) | ((uint)(s3 & 0xff) << 24);
            ((uint*)hq)[(size_t)node * 16 + lane] = packed;
        }
        if (lane == 0) {
            float dv = dn[node];
            gdd[node]  = make_float2(a, dv);
            gss4[node] = make_float4(b, dv, m / 127.0f, 0.f);
        }
    }
}

// ---------- standalone gates (fallback path only) ----------
__global__ void fa_node_gates(const float* __restrict__ h,
                              const float* __restrict__ gate_W,
                              const float* __restrict__ dn,
                              float2* __restrict__ gdd,
                              float4* __restrict__ gss4,
                              int N) {
    int gid  = blockIdx.x * blockDim.x + threadIdx.x;
    int node = gid >> 6;
    int lane = threadIdx.x & 63;
    if (node >= N) return;
    float x = h[(size_t)node * DIM + lane];
    float a = x * gate_W[lane];
    float b = x * gate_W[DIM + lane];
    #pragma unroll
    for (int off = 32; off >= 1; off >>= 1) {
        a += __shfl_xor(a, off, 64);
        b += __shfl_xor(b, off, 64);
    }
    if (lane == 0) {
        float dv = dn[node];
        gdd[node]  = make_float2(a, dv);
        gss4[node] = make_float4(b, dv, 0.f, 0.f);
    }
}

// ---------- scan A: per-bucket exclusive prefix over SORTB blocks ----------
__global__ void fa_sort_scanA(int* __restrict__ cnt, int* __restrict__ bktot) {
    __shared__ int sc[SORTB];
    int bk  = blockIdx.x;
    int tid = threadIdx.x;                        // SORTB threads
    int v = cnt[tid * MAXBK + bk];
    sc[tid] = v;
    __syncthreads();
    for (int dd = 1; dd < SORTB; dd <<= 1) {
        int t = (tid >= dd) ? sc[tid - dd] : 0;
        __syncthreads();
        sc[tid] += t;
        __syncthreads();
    }
    cnt[tid * MAXBK + bk] = sc[tid] - v;
    if (tid == SORTB - 1) bktot[bk] = sc[tid];
}

// ---------- scan B: exclusive scan of bucket totals (4 items/thread, 512 thr) ----------
__global__ void fa_sort_scanB(const int* __restrict__ bktot, int* __restrict__ bkoff, int nbk) {
    __shared__ int sc[512];
    int tid = threadIdx.x;
    int base = tid * 4;
    int v[4];
    int s = 0;
    #pragma unroll
    for (int k = 0; k < 4; ++k) {
        int idx = base + k;
        v[k] = (idx < nbk) ? bktot[idx] : 0;
        s += v[k];
    }
    sc[tid] = s;
    __syncthreads();
    for (int dd = 1; dd < 512; dd <<= 1) {
        int t = (tid >= dd) ? sc[tid - dd] : 0;
        __syncthreads();
        sc[tid] += t;
        __syncthreads();
    }
    int run = sc[tid] - s;
    #pragma unroll
    for (int k = 0; k < 4; ++k) {
        int idx = base + k;
        if (idx < nbk) bkoff[idx] = run;
        run += v[k];
    }
}

// ---------- place 4-byte record (src<<6 | local_dst); no gate math ----------
__global__ void fa_place(const int* __restrict__ esrc, const int* __restrict__ edst,
                         const int* __restrict__ cnt, const int* __restrict__ bkoff,
                         int* __restrict__ pairs, int E, int nbk) {
    __shared__ int lcur[MAXBK];
    int tid = threadIdx.x;                        // PLACET threads
    for (int i = tid; i < nbk; i += blockDim.x)
        lcur[i] = bkoff[i] + cnt[blockIdx.x * MAXBK + i];
    __syncthreads();
    int chunk = (E + gridDim.x - 1) / gridDim.x;
    int c0 = blockIdx.x * chunk;
    int c1 = min(E, c0 + chunk);
    for (int i = c0 + tid; i < c1; i += blockDim.x) {
        int t = edst[i];
        int s = esrc[i];
        int pos = atomicAdd(&lcur[t >> BKSH], 1);       // LDS atomic
        pairs[pos] = (s << BKSH) | (t & (BKN - 1));
    }
}

// ---------- fused: LDS counting sort + gate compute + quarter-wave int8 gather ----------
__global__ __launch_bounds__(512, 4)
void fa_gather9(const unsigned char* __restrict__ hq,
                const float2* __restrict__ gdd, const float4* __restrict__ gss4,
                const float* __restrict__ gate_b,
                const int* __restrict__ bkoff, const int* __restrict__ bktot,
                const int* __restrict__ pairs,
                float* __restrict__ z, int N) {
    __shared__ int2 buf2[CAP];                   // 32 KB ({src, ev} sorted by node)
    __shared__ float2 gdl[BKN];                  // dst-side {gd, d} for this bucket
    __shared__ int hist[BKN];
    __shared__ int cur[BKN];
    __shared__ int offl[BKN + 1];
    int bk  = blockIdx.x;
    int tid = threadIdx.x;                       // 512 threads = 8 waves
    int s0  = bkoff[bk];
    int c   = bktot[bk];
    int n0  = bk << BKSH;
    int wid  = tid >> 6;
    int lane = tid & 63;
    float gb = gate_b[0];
    if (tid < BKN) {
        int node = n0 + tid;
        gdl[tid]  = (node < N) ? gdd[node] : make_float2(0.f, 0.f);
        hist[tid] = 0;
    }
    __syncthreads();
    if (c <= CAP) {
        // pass 1: histogram from global pairs
        for (int i = tid; i < c; i += 512)
            atomicAdd(&hist[pairs[s0 + i] & (BKN - 1)], 1);
        __syncthreads();
        if (tid < BKN) cur[tid] = hist[tid];
        __syncthreads();
        #pragma unroll
        for (int dd = 1; dd < BKN; dd <<= 1) {
            int t = (tid < BKN && tid >= dd) ? cur[tid - dd] : 0;
            __syncthreads();
            if (tid < BKN) cur[tid] += t;
            __syncthreads();
        }
        if (tid < BKN) {
            offl[tid + 1] = cur[tid];            // inclusive -> offl[t+1]
            cur[tid] -= hist[tid];               // exclusive cursor
            if (tid == 0) offl[0] = 0;
        }
        __syncthreads();
        // pass 2: permute into node-sorted buf2 (pairs L2-hot); ev folds src scale
        for (int i = tid; i < c; i += 512) {
            int r  = pairs[s0 + i];
            int lt = r & (BKN - 1);
            int s  = r >> BKSH;
            float4 bs = gss4[s];
            float2 ad = gdl[lt];
            float g  = fast_tanh(ad.x + bs.x + gb);
            float ev = g * ad.y * bs.y * bs.z;   // includes int8 dequant scale
            int p = atomicAdd(&cur[lt], 1);
            buf2[p] = make_int2(s, __float_as_int(ev));
        }
        __syncthreads();
        // quarter-wave gather: 16 lanes per record (4 int8 dims/lane),
        // 4 quarters x 4-deep unroll -> 16 records in flight per wave
        int qid = lane >> 4;                     // quarter 0..3
        int l16 = lane & 15;
        for (int ln = wid; ln < BKN; ln += 8) {
            int node = n0 + ln;
            if (node >= N) break;
            int j   = offl[ln];
            int end = offl[ln + 1];
            float4 a0 = make_float4(0.f, 0.f, 0.f, 0.f);
            float4 a1 = a0, a2 = a0, a3 = a0;
            for (; j + 16 <= end; j += 16) {
                int2 p0 = buf2[j + qid];
                int2 p1 = buf2[j + qid + 4];
                int2 p2 = buf2[j + qid + 8];
                int2 p3 = buf2[j + qid + 12];
                uint q0 = ((const uint*)(hq + (size_t)p0.x * DIM))[l16];
                uint q1 = ((const uint*)(hq + (size_t)p1.x * DIM))[l16];
                uint q2 = ((const uint*)(hq + (size_t)p2.x * DIM))[l16];
                uint q3 = ((const uint*)(hq + (size_t)p3.x * DIM))[l16];
                float e0 = __int_as_float(p0.y);
                float e1 = __int_as_float(p1.y);
                float e2 = __int_as_float(p2.y);
                float e3 = __int_as_float(p3.y);
                float4 h0 = i8x4_unpack(q0);
                float4 h1 = i8x4_unpack(q1);
                float4 h2 = i8x4_unpack(q2);
                float4 h3 = i8x4_unpack(q3);
                a0.x += h0.x * e0; a0.y += h0.y * e0; a0.z += h0.z * e0; a0.w += h0.w * e0;
                a1.x += h1.x * e1; a1.y += h1.y * e1; a1.z += h1.z * e1; a1.w += h1.w * e1;
                a2.x += h2.x * e2; a2.y += h2.y * e2; a2.z += h2.z * e2; a2.w += h2.w * e2;
                a3.x += h3.x * e3; a3.y += h3.y * e3; a3.z += h3.z * e3; a3.w += h3.w * e3;
            }
            for (; j + 4 <= end; j += 4) {
                int2 p = buf2[j + qid];
                uint q = ((const uint*)(hq + (size_t)p.x * DIM))[l16];
                float e = __int_as_float(p.y);
                float4 hv = i8x4_unpack(q);
                a0.x += hv.x * e; a0.y += hv.y * e; a0.z += hv.z * e; a0.w += hv.w * e;
            }
            int rem = end - j;
            if (rem > 0) {
                int idx = j + (qid < rem ? qid : 0);
                int2 p = buf2[idx];
                float e = (qid < rem) ? __int_as_float(p.y) : 0.f;
                uint q = ((const uint*)(hq + (size_t)p.x * DIM))[l16];
                float4 hv = i8x4_unpack(q);
                a0.x += hv.x * e; a0.y += hv.y * e; a0.z += hv.z * e; a0.w += hv.w * e;
            }
            float4 t;
            t.x = a0.x + a1.x + a2.x + a3.x;
            t.y = a0.y + a1.y + a2.y + a3.y;
            t.z = a0.z + a1.z + a2.z + a3.z;
            t.w = a0.w + a1.w + a2.w + a3.w;
            t.x += __shfl_xor(t.x, 16, 64);  t.x += __shfl_xor(t.x, 32, 64);
            t.y += __shfl_xor(t.y, 16, 64);  t.y += __shfl_xor(t.y, 32, 64);
            t.z += __shfl_xor(t.z, 16, 64);  t.z += __shfl_xor(t.z, 32, 64);
            t.w += __shfl_xor(t.w, 16, 64);  t.w += __shfl_xor(t.w, 32, 64);
            if (qid == 0)
                *(float4*)&z[(size_t)node * DIM + (l16 << 2)] = t;
        }
    } else {
        // adversarial-skew slow path: filter directly from global (correct, rare)
        for (int ln = wid; ln < BKN; ln += 8) {
            int node = n0 + ln;
            if (node >= N) break;
            float2 ad = gdl[ln];
            float acc = 0.f;
            for (int j = s0; j < s0 + c; ++j) {
                int r = pairs[j];
                if ((r & (BKN - 1)) == ln) {
                    int s = r >> BKSH;
                    float4 bs = gss4[s];
                    float g  = fast_tanh(ad.x + bs.x + gb);
                    uint qw = ((const uint*)(hq + (size_t)s * DIM))[lane >> 2];
                    int qv = (int)(qw << ((3 - (lane & 3)) * 8)) >> 24;
                    acc += (float)qv * (g * ad.y * bs.y * bs.z);
                }
            }
            z[(size_t)node * DIM + lane] = acc;
        }
    }
}

// ---------- fallback: atomic scatter (uses f32 h; ignores scale) ----------
__global__ void fa_edge_scatter_atomic(const float* __restrict__ h,
                                       const float2* __restrict__ gdd,
                                       const float4* __restrict__ gss4,
                                       const int* __restrict__ esrc,
                                       const int* __restrict__ edst,
                                       const float* __restrict__ gate_b,
                                       float* __restrict__ z, int E) {
    int gid  = blockIdx.x * blockDim.x + threadIdx.x;
    int edge = gid >> 6;
    int lane = threadIdx.x & 63;
    if (edge >= E) return;
    int s = esrc[edge];
    int t = edst[edge];
    float2 ad = gdd[t];
    float4 bs = gss4[s];
    float g  = fast_tanh(ad.x + bs.x + gate_b[0]);
    float ev = g * ad.y * bs.y;
    atomicAdd(&z[(size_t)t * DIM + lane], h[(size_t)s * DIM + lane] * ev);
}

extern "C" void kernel_launch(void* const* d_in, const int* in_sizes, int n_in,
                              void* d_out, int out_size, void* d_ws, size_t ws_size,
                              hipStream_t stream) {
    const float* h      = (const float*)d_in[0];
    const float* dn     = (const float*)d_in[1];
    const float* gate_W = (const float*)d_in[2];
    const float* gate_b = (const float*)d_in[3];
    const int*   esrc   = (const int*)d_in[4];
    const int*   edst   = (const int*)d_in[5];
    float*       z      = (float*)d_out;

    int N = in_sizes[1];
    int E = in_sizes[4];
    int nbk = (N + BKN - 1) >> BKSH;

    // workspace layout
    char* w = (char*)d_ws;
    float2* gdd  = (float2*)w;         w += (size_t)N * 8;
    float4* gss4 = (float4*)w;         w += (size_t)N * 16;
    int*   bktot = (int*)w;            w += (size_t)MAXBK * 4;
    int*   bkoff = (int*)w;            w += (size_t)MAXBK * 4;
    int*   cnt   = (int*)w;            w += (size_t)SORTB * MAXBK * 4;  // 1.64 MB
    w = (char*)(((uintptr_t)w + 63) & ~(uintptr_t)63);
    int*  pairs  = (int*)w;            w += ((size_t)E + 64) * 4;
    unsigned char* hq = (unsigned char*)w;
    w += (size_t)N * DIM;              // 6.4 MB int8 table
    size_t required = (size_t)(w - (char*)d_ws);
    size_t atomic_required = (size_t)N * 24;

    bool use_sort = (ws_size >= required) && (nbk <= MAXBK);

    if (use_sort) {
        int gatesBlocks = (N + 7) / 8;           // 512 thr = 8 nodes/block
        fa_gates_hist<<<SORTB + gatesBlocks, 512, 0, stream>>>(
            h, gate_W, dn, gdd, gss4, hq, edst, cnt, E, N, SORTB);
        fa_sort_scanA<<<nbk, SORTB, 0, stream>>>(cnt, bktot);
        fa_sort_scanB<<<1, 512, 0, stream>>>(bktot, bkoff, nbk);
        fa_place<<<SORTB, PLACET, 0, stream>>>(esrc, edst, cnt, bkoff, pairs, E, nbk);
        fa_gather9<<<nbk, 512, 0, stream>>>(hq, gdd, gss4, gate_b, bkoff, bktot,
                                            pairs, z, N);
    } else if (ws_size >= atomic_required) {
        fa_node_gates<<<(N + 3) / 4, 256, 0, stream>>>(h, gate_W, dn, gdd, gss4, N);
        hipMemsetAsync(z, 0, (size_t)out_size * sizeof(float), stream);
        fa_edge_scatter_atomic<<<(E + 3) / 4, 256, 0, stream>>>(h, gdd, gss4, esrc,
                                                                edst, gate_b, z, E);
    }
}